// Round 1
// baseline (1038.177 us; speedup 1.0000x reference)
//
#include <hip/hip_runtime.h>
#include <hip/hip_bf16.h>

namespace {

constexpr int H      = 256;  // model dim (heads*att_size)
constexpr int C      = 259;  // k/v channel dim (H+3)
constexpr int CP     = 260;  // padded channel dim (float4-aligned rows)
constexpr int E      = 32;   // neighbors
constexpr int NHEAD  = 8;
constexpr int NB     = 4;    // nodes per block
constexpr float SCALE = 0.17677669529663687f; // 1/sqrt(32)

__global__ __launch_bounds__(256, 2) void mha_neigh_kernel(
    const float* __restrict__ q, const float* __restrict__ kk, const float* __restrict__ vv,
    const float* __restrict__ Wq, const float* __restrict__ Wk,
    const float* __restrict__ Wv, const float* __restrict__ Wo,
    float* __restrict__ outp, int n)
{
    __shared__ __align__(16) float k_st[E * CP];            // 33280 B, staged k for current node
    __shared__ __align__(16) float w_lds[NB * NHEAD * CP];  // 33280 B, w then vbar (per node slot)
    __shared__ __align__(16) float qp_lds[NB * H];          // 4096 B
    __shared__ __align__(16) float red_out[8 * 256];        // 8192 B: simi partials, later out
    __shared__ __align__(16) float att_lds[E * NHEAD];      // 1024 B, att[e][h]

    const int t    = threadIdx.x;
    const int wv   = t >> 6;
    const int lane = t & 63;
    const int n0   = blockIdx.x * NB;

    int node[NB];
    #pragma unroll
    for (int nb = 0; nb < NB; ++nb) {
        int nn = n0 + nb;
        node[nb] = (nn < n) ? nn : (n - 1);
    }

    // ---- P1: qp[nb][t] = sum_c q[node][c] * Wq[t][c]  (thread t owns Wq row t)
    {
        float acc[NB] = {};
        const float4* Wq4 = (const float4*)Wq;
        const float4* q4[NB];
        #pragma unroll
        for (int nb = 0; nb < NB; ++nb) q4[nb] = (const float4*)(q + (size_t)node[nb] * H);
        for (int i = 0; i < 64; ++i) {
            float4 wq = Wq4[t * 64 + i];
            #pragma unroll
            for (int nb = 0; nb < NB; ++nb) {
                float4 qv = q4[nb][i];   // block-uniform -> scalar load
                acc[nb] += wq.x * qv.x + wq.y * qv.y + wq.z * qv.z + wq.w * qv.w;
            }
        }
        #pragma unroll
        for (int nb = 0; nb < NB; ++nb) qp_lds[nb * H + t] = acc[nb];
    }
    __syncthreads();

    // ---- P2: w[nb][h][c] = sum_d qp[nb][h*32+d] * Wk[h*32+d][c]
    // thread t: h = t>>5, c0 = t&31; covers c = c0 + 32j, coalesced Wk reads
    {
        const int h  = t >> 5;
        const int c0 = t & 31;
        float acc[9 * NB] = {};
        for (int d = 0; d < 32; ++d) {
            const float* wkrow = Wk + (size_t)(h * 32 + d) * C;
            float qpv[NB];
            #pragma unroll
            for (int nb = 0; nb < NB; ++nb) qpv[nb] = qp_lds[nb * H + h * 32 + d];
            #pragma unroll
            for (int j = 0; j < 9; ++j) {
                int c = c0 + 32 * j;
                if (c < C) {
                    float wkv = wkrow[c];
                    #pragma unroll
                    for (int nb = 0; nb < NB; ++nb) acc[j * NB + nb] += wkv * qpv[nb];
                }
            }
        }
        #pragma unroll
        for (int j = 0; j < 9; ++j) {
            int c = c0 + 32 * j;
            #pragma unroll
            for (int nb = 0; nb < NB; ++nb) {
                if (c < C)       w_lds[(nb * NHEAD + h) * CP + c]   = acc[j * NB + nb];
                else if (c == C) w_lds[(nb * NHEAD + h) * CP + 259] = 0.0f;  // zero pad col
            }
        }
    }
    __syncthreads();

    // ---- P3: per node: stage k -> simi -> softmax -> vbar (vbar overwrites w[nb] slot)
    for (int nb = 0; nb < NB; ++nb) {
        const float* kbase = kk + (size_t)node[nb] * (E * C);

        // stage k rows [wv*8, wv*8+8) into padded LDS, coalesced
        #pragma unroll
        for (int er = 0; er < 8; ++er) {
            int e = wv * 8 + er;
            const float* krow = kbase + e * C;
            float x0 = krow[lane];
            float x1 = krow[64 + lane];
            float x2 = krow[128 + lane];
            float x3 = krow[192 + lane];
            k_st[e * CP + lane]       = x0;
            k_st[e * CP + 64 + lane]  = x1;
            k_st[e * CP + 128 + lane] = x2;
            k_st[e * CP + 192 + lane] = x3;
            if (lane < 4) k_st[e * CP + 256 + lane] = (lane < 3) ? krow[256 + lane] : 0.0f;
        }
        __syncthreads();

        // simi partials: lane = e + 32*ci; chunk group g = wv*2+ci handles m = g, g+8, ...
        {
            const int e  = lane & 31;
            const int ci = lane >> 5;
            const int g  = wv * 2 + ci;
            float acc[NHEAD] = {};
            for (int m = g; m < 65; m += 8) {
                float4 k4 = *(const float4*)&k_st[e * CP + 4 * m];
                const float* wbase = &w_lds[(nb * NHEAD) * CP + 4 * m];
                #pragma unroll
                for (int h = 0; h < NHEAD; ++h) {
                    float4 w4 = *(const float4*)&wbase[h * CP];
                    acc[h] += k4.x * w4.x + k4.y * w4.y + k4.z * w4.z + k4.w * w4.w;
                }
            }
            #pragma unroll
            for (int h = 0; h < NHEAD; ++h) red_out[g * 256 + h * 32 + e] = acc[h];
        }
        __syncthreads();

        // softmax over e: thread t -> (h = t>>5, e = t&31); reduce within 32-lane groups
        {
            float s = 0.f;
            #pragma unroll
            for (int g = 0; g < 8; ++g) s += red_out[g * 256 + t];
            s *= SCALE;
            float mx = s;
            #pragma unroll
            for (int off = 16; off >= 1; off >>= 1) mx = fmaxf(mx, __shfl_xor(mx, off, 64));
            float p = __expf(s - mx);
            float sum = p;
            #pragma unroll
            for (int off = 16; off >= 1; off >>= 1) sum += __shfl_xor(sum, off, 64);
            att_lds[(t & 31) * NHEAD + (t >> 5)] = p / sum;
        }
        __syncthreads();

        // vbar[h][c] = sum_e att[e][h] * v[e][c]; thread owns c = t (+ tail c=256+t for t<3)
        {
            const float* vbase = vv + (size_t)node[nb] * (E * C);
            float acc[NHEAD]  = {};
            float acc2[NHEAD] = {};
            for (int e = 0; e < E; ++e) {
                const float4* a4 = (const float4*)&att_lds[e * NHEAD];
                float4 a0 = a4[0];
                float4 a1 = a4[1];
                float x = vbase[e * C + t];
                acc[0] += a0.x * x; acc[1] += a0.y * x; acc[2] += a0.z * x; acc[3] += a0.w * x;
                acc[4] += a1.x * x; acc[5] += a1.y * x; acc[6] += a1.z * x; acc[7] += a1.w * x;
                if (t < 3) {
                    float x2 = vbase[e * C + 256 + t];
                    acc2[0] += a0.x * x2; acc2[1] += a0.y * x2; acc2[2] += a0.z * x2; acc2[3] += a0.w * x2;
                    acc2[4] += a1.x * x2; acc2[5] += a1.y * x2; acc2[6] += a1.z * x2; acc2[7] += a1.w * x2;
                }
            }
            float* wrow = &w_lds[(nb * NHEAD) * CP];
            #pragma unroll
            for (int h = 0; h < NHEAD; ++h) wrow[h * CP + t] = acc[h];
            if (t < 3) {
                #pragma unroll
                for (int h = 0; h < NHEAD; ++h) wrow[h * CP + 256 + t] = acc2[h];
            }
        }
        __syncthreads();
    }

    // ---- P4: out[nb][t] = sum_c vbar[nb][h][c] * Wv[t][c],  h = t>>5 (thread t owns Wv row t)
    {
        const int h = t >> 5;
        const float* wvrow = Wv + (size_t)t * C;
        float acc[NB] = {};
        for (int c4 = 0; c4 < 64; ++c4) {
            float w0 = wvrow[4 * c4 + 0];
            float w1 = wvrow[4 * c4 + 1];
            float w2 = wvrow[4 * c4 + 2];
            float w3 = wvrow[4 * c4 + 3];
            #pragma unroll
            for (int nb = 0; nb < NB; ++nb) {
                float4 vb = *(const float4*)&w_lds[(nb * NHEAD + h) * CP + 4 * c4];
                acc[nb] += w0 * vb.x + w1 * vb.y + w2 * vb.z + w3 * vb.w;
            }
        }
        for (int c = 256; c < 259; ++c) {
            float wvv = wvrow[c];
            #pragma unroll
            for (int nb = 0; nb < NB; ++nb) acc[nb] += wvv * w_lds[(nb * NHEAD + h) * CP + c];
        }
        #pragma unroll
        for (int nb = 0; nb < NB; ++nb) red_out[nb * 256 + t] = acc[nb];  // out_lds aliases red
    }
    __syncthreads();

    // ---- P5: final[nb][t] = sum_dd out[nb][dd] * Wo[t][dd]  (thread t owns Wo row t)
    {
        float acc[NB] = {};
        const float4* Wo4 = (const float4*)Wo;
        for (int i = 0; i < 64; ++i) {
            float4 wo = Wo4[t * 64 + i];
            #pragma unroll
            for (int nb = 0; nb < NB; ++nb) {
                float4 o4 = *(const float4*)&red_out[nb * 256 + 4 * i];
                acc[nb] += wo.x * o4.x + wo.y * o4.y + wo.z * o4.z + wo.w * o4.w;
            }
        }
        #pragma unroll
        for (int nb = 0; nb < NB; ++nb) {
            if (n0 + nb < n) outp[(size_t)(n0 + nb) * H + t] = acc[nb];
        }
    }
}

} // anonymous namespace

extern "C" void kernel_launch(void* const* d_in, const int* in_sizes, int n_in,
                              void* d_out, int out_size, void* d_ws, size_t ws_size,
                              hipStream_t stream) {
    const float* q  = (const float*)d_in[0];
    const float* k  = (const float*)d_in[1];
    const float* v  = (const float*)d_in[2];
    const float* Wq = (const float*)d_in[3];
    const float* Wk = (const float*)d_in[4];
    const float* Wv = (const float*)d_in[5];
    const float* Wo = (const float*)d_in[6];
    float* out = (float*)d_out;

    const int n = in_sizes[0] / H;            // 10000 nodes
    const int blocks = (n + NB - 1) / NB;     // 2500

    mha_neigh_kernel<<<dim3(blocks), dim3(256), 0, stream>>>(
        q, k, v, Wq, Wk, Wv, Wo, out, n);
}

// Round 2
// 372.998 us; speedup vs baseline: 2.7833x; 2.7833x over previous
//
#include <hip/hip_runtime.h>
#include <hip/hip_bf16.h>

namespace {

constexpr int H      = 256;  // model dim (heads*att_size)
constexpr int C      = 259;  // k/v channel dim (H+3)
constexpr int CP     = 260;  // padded channel dim for LDS rows
constexpr int E      = 32;   // neighbors
constexpr int NHEAD  = 8;
constexpr int NB     = 4;    // nodes per block
constexpr float SCALE = 0.17677669529663687f; // 1/sqrt(32)

__global__ __launch_bounds__(256, 4) void mha_neigh_kernel(
    const float* __restrict__ q, const float* __restrict__ kk, const float* __restrict__ vv,
    const float* __restrict__ Wq, const float* __restrict__ Wk,
    const float* __restrict__ Wv, const float* __restrict__ Wo,
    float* __restrict__ outp, int n)
{
    // LDS budget: 33280 + 4096 = 37376 B -> 4 blocks/CU (16 waves/CU)
    __shared__ __align__(16) float w_lds[NB * NHEAD * CP]; // w (simi weights), then vbar
    __shared__ __align__(16) float uni[NB * 256];          // qp -> att -> out (disjoint lifetimes)

    const int t  = threadIdx.x;
    const int n0 = blockIdx.x * NB;

    int node[NB];
    #pragma unroll
    for (int nb = 0; nb < NB; ++nb) {
        int nn = n0 + nb;
        node[nb] = (nn < n) ? nn : (n - 1);
    }

    // ---- P1: qp[nb][t] = sum_c q[node][c] * Wq[t][c]  (thread t owns Wq row t)
    {
        float acc[NB] = {};
        const float4* Wq4 = (const float4*)Wq;
        for (int i = 0; i < 64; ++i) {
            float4 wq = Wq4[t * 64 + i];
            #pragma unroll
            for (int nb = 0; nb < NB; ++nb) {
                float4 qv = *(const float4*)(q + (size_t)node[nb] * H + 4 * i); // uniform -> s_load
                acc[nb] += wq.x * qv.x + wq.y * qv.y + wq.z * qv.z + wq.w * qv.w;
            }
        }
        #pragma unroll
        for (int nb = 0; nb < NB; ++nb) uni[nb * 256 + t] = acc[nb];
    }
    __syncthreads();

    // ---- P2: w[nb][h][c] = sum_d qp[nb][h*32+d] * Wk[h*32+d][c]
    {
        const int h  = t >> 5;
        const int c0 = t & 31;
        float acc[9 * NB] = {};
        for (int d = 0; d < 32; ++d) {
            const float* wkrow = Wk + (size_t)(h * 32 + d) * C;
            float qpv[NB];
            #pragma unroll
            for (int nb = 0; nb < NB; ++nb) qpv[nb] = uni[nb * 256 + h * 32 + d];
            #pragma unroll
            for (int j = 0; j < 9; ++j) {
                int c = c0 + 32 * j;
                if (c < C) {
                    float wkv = wkrow[c];
                    #pragma unroll
                    for (int nb = 0; nb < NB; ++nb) acc[j * NB + nb] += wkv * qpv[nb];
                }
            }
        }
        #pragma unroll
        for (int j = 0; j < 9; ++j) {
            int c = c0 + 32 * j;
            if (c < C) {
                #pragma unroll
                for (int nb = 0; nb < NB; ++nb) w_lds[(nb * NHEAD + h) * CP + c] = acc[j * NB + nb];
            }
        }
    }
    __syncthreads();

    // ---- P3a: simi for ALL nodes, direct from global k (no LDS staging).
    // thread -> (e = t>>3, j = t&7); j covers c = j*4 + 32m (float4), m=0..7
    {
        const int e = t >> 3;
        const int j = t & 7;
        #pragma unroll 1
        for (int nb = 0; nb < NB; ++nb) {
            const float* krow = kk + (size_t)node[nb] * (E * C) + (size_t)e * C;
            float acc[NHEAD] = {};
            #pragma unroll
            for (int m = 0; m < 8; ++m) {
                float4 k4 = *(const float4*)&krow[j * 4 + 32 * m];
                const float* wb = &w_lds[(nb * NHEAD) * CP + j * 4 + 32 * m];
                #pragma unroll
                for (int h = 0; h < NHEAD; ++h) {
                    float4 w4 = *(const float4*)&wb[h * CP];
                    acc[h] += k4.x * w4.x + k4.y * w4.y + k4.z * w4.z + k4.w * w4.w;
                }
            }
            if (j == 0) { // tail channels 256..258
                #pragma unroll
                for (int ct = 0; ct < 3; ++ct) {
                    float kx = krow[256 + ct];
                    #pragma unroll
                    for (int h = 0; h < NHEAD; ++h)
                        acc[h] += kx * w_lds[(nb * NHEAD + h) * CP + 256 + ct];
                }
            }
            // reduce over the 8 c-slots (lanes j=0..7 within each e-group)
            #pragma unroll
            for (int h = 0; h < NHEAD; ++h) {
                float s = acc[h];
                s += __shfl_xor(s, 1, 64);
                s += __shfl_xor(s, 2, 64);
                s += __shfl_xor(s, 4, 64);
                acc[h] = s;
            }
            float myv = 0.0f;
            #pragma unroll
            for (int h = 0; h < NHEAD; ++h) myv = (j == h) ? acc[h] : myv;
            uni[nb * 256 + e * 8 + j] = myv * SCALE;   // att slot: [nb][e][h=j]
        }
    }
    __syncthreads();

    // ---- P3b: softmax over e per head, in place; thread -> (h = t>>5, e32 = t&31)
    {
        const int h   = t >> 5;
        const int e32 = t & 31;
        #pragma unroll
        for (int nb = 0; nb < NB; ++nb) {
            float s = uni[nb * 256 + e32 * 8 + h];
            float mx = s;
            #pragma unroll
            for (int off = 16; off >= 1; off >>= 1) mx = fmaxf(mx, __shfl_xor(mx, off, 64));
            float p = __expf(s - mx);
            float sum = p;
            #pragma unroll
            for (int off = 16; off >= 1; off >>= 1) sum += __shfl_xor(sum, off, 64);
            uni[nb * 256 + e32 * 8 + h] = p / sum;
        }
    }
    __syncthreads();

    // ---- P3c: vbar[nb][h][c] = sum_e att[e][h] * v[e][c]; thread owns c = t
    {
        #pragma unroll 1
        for (int nb = 0; nb < NB; ++nb) {
            const float* vrow = vv + (size_t)node[nb] * (E * C);
            float acc[NHEAD] = {};
            for (int e = 0; e < E; ++e) {
                const float4* a4 = (const float4*)&uni[nb * 256 + e * 8];
                float4 a0 = a4[0];
                float4 a1 = a4[1];
                float x = vrow[e * C + t];
                acc[0] += a0.x * x; acc[1] += a0.y * x; acc[2] += a0.z * x; acc[3] += a0.w * x;
                acc[4] += a1.x * x; acc[5] += a1.y * x; acc[6] += a1.z * x; acc[7] += a1.w * x;
            }
            #pragma unroll
            for (int h = 0; h < NHEAD; ++h) w_lds[(nb * NHEAD + h) * CP + t] = acc[h];
            if (t < 3) { // tail channels, only wave 0 pays (execz skip elsewhere)
                float a2[NHEAD] = {};
                for (int e = 0; e < E; ++e) {
                    const float4* a4 = (const float4*)&uni[nb * 256 + e * 8];
                    float4 a0 = a4[0];
                    float4 a1 = a4[1];
                    float x2 = vrow[e * C + 256 + t];
                    a2[0] += a0.x * x2; a2[1] += a0.y * x2; a2[2] += a0.z * x2; a2[3] += a0.w * x2;
                    a2[4] += a1.x * x2; a2[5] += a1.y * x2; a2[6] += a1.z * x2; a2[7] += a1.w * x2;
                }
                #pragma unroll
                for (int h = 0; h < NHEAD; ++h) w_lds[(nb * NHEAD + h) * CP + 256 + t] = a2[h];
            }
        }
    }
    __syncthreads();

    // ---- P4: out[nb][t] = sum_c vbar[nb][h][c] * Wv[t][c],  h = t>>5
    {
        const int h = t >> 5;
        const float* wvrow = Wv + (size_t)t * C;   // row base NOT 16B aligned -> scalar loads
        float acc[NB] = {};
        for (int c4 = 0; c4 < 64; ++c4) {
            float w0 = wvrow[4 * c4 + 0];
            float w1 = wvrow[4 * c4 + 1];
            float w2 = wvrow[4 * c4 + 2];
            float w3 = wvrow[4 * c4 + 3];
            #pragma unroll
            for (int nb = 0; nb < NB; ++nb) {
                float4 vb = *(const float4*)&w_lds[(nb * NHEAD + h) * CP + 4 * c4];
                acc[nb] += w0 * vb.x + w1 * vb.y + w2 * vb.z + w3 * vb.w;
            }
        }
        #pragma unroll
        for (int c = 256; c < 259; ++c) {
            float wvv = wvrow[c];
            #pragma unroll
            for (int nb = 0; nb < NB; ++nb) acc[nb] += wvv * w_lds[(nb * NHEAD + h) * CP + c];
        }
        #pragma unroll
        for (int nb = 0; nb < NB; ++nb) uni[nb * 256 + t] = acc[nb];   // out slot (att dead)
    }
    __syncthreads();

    // ---- P5: final[nb][t] = sum_dd out[nb][dd] * Wo[t][dd]
    {
        float acc[NB] = {};
        const float4* Wo4 = (const float4*)Wo;
        for (int i = 0; i < 64; ++i) {
            float4 wo = Wo4[t * 64 + i];
            #pragma unroll
            for (int nb = 0; nb < NB; ++nb) {
                float4 o4 = *(const float4*)&uni[nb * 256 + 4 * i];
                acc[nb] += wo.x * o4.x + wo.y * o4.y + wo.z * o4.z + wo.w * o4.w;
            }
        }
        #pragma unroll
        for (int nb = 0; nb < NB; ++nb) {
            if (n0 + nb < n) outp[(size_t)(n0 + nb) * H + t] = acc[nb];
        }
    }
}

} // anonymous namespace

extern "C" void kernel_launch(void* const* d_in, const int* in_sizes, int n_in,
                              void* d_out, int out_size, void* d_ws, size_t ws_size,
                              hipStream_t stream) {
    const float* q  = (const float*)d_in[0];
    const float* k  = (const float*)d_in[1];
    const float* v  = (const float*)d_in[2];
    const float* Wq = (const float*)d_in[3];
    const float* Wk = (const float*)d_in[4];
    const float* Wv = (const float*)d_in[5];
    const float* Wo = (const float*)d_in[6];
    float* out = (float*)d_out;

    const int n = in_sizes[0] / H;            // 10000 nodes
    const int blocks = (n + NB - 1) / NB;     // 2500

    mha_neigh_kernel<<<dim3(blocks), dim3(256), 0, stream>>>(
        q, k, v, Wq, Wk, Wv, Wo, out, n);
}

// Round 3
// 305.534 us; speedup vs baseline: 3.3979x; 1.2208x over previous
//
#include <hip/hip_runtime.h>
#include <hip/hip_bf16.h>

namespace {

constexpr int H      = 256;  // model dim (heads*att_size)
constexpr int C      = 259;  // k/v channel dim (H+3)
constexpr int CP     = 260;  // padded channel dim for LDS rows (1040 B, 16B-aligned)
constexpr int E      = 32;   // neighbors
constexpr int NHEAD  = 8;
constexpr int NB     = 4;    // nodes per block
constexpr float SCALE = 0.17677669529663687f; // 1/sqrt(32)

__device__ __forceinline__ float dot4(float4 a, float4 b) {
    return a.x * b.x + a.y * b.y + a.z * b.z + a.w * b.w;
}

__global__ __launch_bounds__(256, 4) void mha_neigh_kernel(
    const float* __restrict__ q, const float* __restrict__ kk, const float* __restrict__ vv,
    const float* __restrict__ Wq, const float* __restrict__ Wk,
    const float* __restrict__ Wv, const float* __restrict__ Wo,
    float* __restrict__ outp, int n)
{
    // 33280 + 4096 = 37376 B -> 4 blocks/CU (16 waves/CU)
    __shared__ __align__(16) float w_lds[NB * NHEAD * CP]; // q-stage -> w -> vbar
    __shared__ __align__(16) float uni[NB * 256];          // qp -> att -> out

    const int t    = threadIdx.x;
    const int wv   = t >> 6;
    const int lane = t & 63;
    const int dr   = lane >> 3;  // row-octet index 0..7
    const int cs   = lane & 7;   // c-chunk index 0..7
    const int n0   = blockIdx.x * NB;

    int node[NB];
    #pragma unroll
    for (int nb = 0; nb < NB; ++nb) {
        int nn = n0 + nb;
        node[nb] = (nn < n) ? nn : (n - 1);
    }

    // ---- P0: stage q into LDS (aliases w_lds; dead before P2 writes w)
    float* q_st = w_lds;
    #pragma unroll
    for (int nb = 0; nb < NB; ++nb) q_st[nb * 256 + t] = q[(size_t)node[nb] * H + t];
    __syncthreads();

    // ---- P1: qp[nb][row] = sum_c Wq[row][c] * q[nb][c]   (coalesced split-K)
    // pass p: rows p*32 + wv*8 + dr; lane covers c = cs*4 + 32m
    #pragma unroll
    for (int p = 0; p < 8; ++p) {
        const int row = p * 32 + wv * 8 + dr;
        const float* wqrow = Wq + (size_t)row * H;
        float a0 = 0.f, a1 = 0.f, a2 = 0.f, a3 = 0.f;
        #pragma unroll
        for (int m = 0; m < 8; ++m) {
            float4 wq = *(const float4*)&wqrow[cs * 4 + 32 * m];
            a0 += dot4(wq, *(const float4*)&q_st[0 * 256 + cs * 4 + 32 * m]);
            a1 += dot4(wq, *(const float4*)&q_st[1 * 256 + cs * 4 + 32 * m]);
            a2 += dot4(wq, *(const float4*)&q_st[2 * 256 + cs * 4 + 32 * m]);
            a3 += dot4(wq, *(const float4*)&q_st[3 * 256 + cs * 4 + 32 * m]);
        }
        #pragma unroll
        for (int off = 1; off <= 4; off <<= 1) {
            a0 += __shfl_xor(a0, off, 64);
            a1 += __shfl_xor(a1, off, 64);
            a2 += __shfl_xor(a2, off, 64);
            a3 += __shfl_xor(a3, off, 64);
        }
        float val = (cs == 0) ? a0 : (cs == 1) ? a1 : (cs == 2) ? a2 : a3;
        if (cs < 4) uni[cs * 256 + row] = val;
    }
    __syncthreads();

    // ---- P2: w[nb][h][c] = sum_d qp[nb][h*32+d] * Wk[h*32+d][c]  (coalesced over c)
    {
        const int h  = t >> 5;
        const int c0 = t & 31;
        float acc[9 * NB] = {};
        for (int d = 0; d < 32; ++d) {
            const float* wkrow = Wk + (size_t)(h * 32 + d) * C;
            float qpv[NB];
            #pragma unroll
            for (int nb = 0; nb < NB; ++nb) qpv[nb] = uni[nb * 256 + h * 32 + d];
            #pragma unroll
            for (int j = 0; j < 9; ++j) {
                int c = c0 + 32 * j;
                if (c < C) {
                    float wkv = wkrow[c];
                    #pragma unroll
                    for (int nb = 0; nb < NB; ++nb) acc[j * NB + nb] += wkv * qpv[nb];
                }
            }
        }
        #pragma unroll
        for (int j = 0; j < 9; ++j) {
            int c = c0 + 32 * j;
            if (c < C) {
                #pragma unroll
                for (int nb = 0; nb < NB; ++nb) w_lds[(nb * NHEAD + h) * CP + c] = acc[j * NB + nb];
            }
        }
    }
    __syncthreads();

    // ---- P3a: simi direct from global k; thread -> (e = t>>3, j = t&7)
    {
        const int e = t >> 3;
        const int j = t & 7;
        #pragma unroll 2
        for (int nb = 0; nb < NB; ++nb) {
            const float* krow = kk + (size_t)node[nb] * (E * C) + (size_t)e * C;
            float acc[NHEAD] = {};
            #pragma unroll
            for (int m = 0; m < 8; ++m) {
                float4 k4 = *(const float4*)&krow[j * 4 + 32 * m];
                const float* wb = &w_lds[(nb * NHEAD) * CP + j * 4 + 32 * m];
                #pragma unroll
                for (int h = 0; h < NHEAD; ++h) {
                    float4 w4 = *(const float4*)&wb[h * CP];
                    acc[h] += dot4(k4, w4);
                }
            }
            if (j == 0) { // tail channels 256..258
                #pragma unroll
                for (int ct = 0; ct < 3; ++ct) {
                    float kx = krow[256 + ct];
                    #pragma unroll
                    for (int h = 0; h < NHEAD; ++h)
                        acc[h] += kx * w_lds[(nb * NHEAD + h) * CP + 256 + ct];
                }
            }
            #pragma unroll
            for (int h = 0; h < NHEAD; ++h) {
                float s = acc[h];
                s += __shfl_xor(s, 1, 64);
                s += __shfl_xor(s, 2, 64);
                s += __shfl_xor(s, 4, 64);
                acc[h] = s;
            }
            float myv = 0.0f;
            #pragma unroll
            for (int h = 0; h < NHEAD; ++h) myv = (j == h) ? acc[h] : myv;
            uni[nb * 256 + e * 8 + j] = myv * SCALE;   // att slot [nb][e][h=j]
        }
    }
    __syncthreads();

    // ---- P3b: softmax over e per head, in place; thread -> (h = t>>5, e32 = t&31)
    {
        const int h   = t >> 5;
        const int e32 = t & 31;
        #pragma unroll
        for (int nb = 0; nb < NB; ++nb) {
            float s = uni[nb * 256 + e32 * 8 + h];
            float mx = s;
            #pragma unroll
            for (int off = 16; off >= 1; off >>= 1) mx = fmaxf(mx, __shfl_xor(mx, off, 64));
            float p = __expf(s - mx);
            float sum = p;
            #pragma unroll
            for (int off = 16; off >= 1; off >>= 1) sum += __shfl_xor(sum, off, 64);
            uni[nb * 256 + e32 * 8 + h] = p / sum;
        }
    }
    __syncthreads();

    // ---- P3c: vbar[nb][h][c] = sum_e att[e][h] * v[e][c]; thread owns c = t
    {
        #pragma unroll 1
        for (int nb = 0; nb < NB; ++nb) {
            const float* vrow = vv + (size_t)node[nb] * (E * C);
            float acc[NHEAD] = {};
            #pragma unroll 8
            for (int e = 0; e < E; ++e) {
                const float4* a4 = (const float4*)&uni[nb * 256 + e * 8];
                float4 a0 = a4[0];
                float4 a1 = a4[1];
                float x = vrow[e * C + t];
                acc[0] += a0.x * x; acc[1] += a0.y * x; acc[2] += a0.z * x; acc[3] += a0.w * x;
                acc[4] += a1.x * x; acc[5] += a1.y * x; acc[6] += a1.z * x; acc[7] += a1.w * x;
            }
            #pragma unroll
            for (int h = 0; h < NHEAD; ++h) w_lds[(nb * NHEAD + h) * CP + t] = acc[h];
            if (t < 3) { // tail channels, only wave 0 pays
                float a2[NHEAD] = {};
                for (int e = 0; e < E; ++e) {
                    const float4* a4 = (const float4*)&uni[nb * 256 + e * 8];
                    float4 a0 = a4[0];
                    float4 a1 = a4[1];
                    float x2 = vrow[e * C + 256 + t];
                    a2[0] += a0.x * x2; a2[1] += a0.y * x2; a2[2] += a0.z * x2; a2[3] += a0.w * x2;
                    a2[4] += a1.x * x2; a2[5] += a1.y * x2; a2[6] += a1.z * x2; a2[7] += a1.w * x2;
                }
                #pragma unroll
                for (int h = 0; h < NHEAD; ++h) w_lds[(nb * NHEAD + h) * CP + 256 + t] = a2[h];
            }
        }
    }
    __syncthreads();

    // ---- P4: out[nb][row] = sum_c vbar[nb][h][c] * Wv[row][c]  (coalesced split-K)
    // pass p: rows p*32 + wv*8 + dr => h = p (uniform per pass)
    #pragma unroll
    for (int p = 0; p < 8; ++p) {
        const int row = p * 32 + wv * 8 + dr;
        const int h   = p;
        const float* wvrow = Wv + (size_t)row * C;
        float a0 = 0.f, a1 = 0.f, a2 = 0.f, a3 = 0.f;
        #pragma unroll
        for (int m = 0; m < 8; ++m) {
            float4 wv4 = *(const float4*)&wvrow[cs * 4 + 32 * m];  // misaligned ok
            a0 += dot4(wv4, *(const float4*)&w_lds[(0 * NHEAD + h) * CP + cs * 4 + 32 * m]);
            a1 += dot4(wv4, *(const float4*)&w_lds[(1 * NHEAD + h) * CP + cs * 4 + 32 * m]);
            a2 += dot4(wv4, *(const float4*)&w_lds[(2 * NHEAD + h) * CP + cs * 4 + 32 * m]);
            a3 += dot4(wv4, *(const float4*)&w_lds[(3 * NHEAD + h) * CP + cs * 4 + 32 * m]);
        }
        if (cs == 0) { // tail channels 256..258 folded in before the reduce
            #pragma unroll
            for (int ct = 0; ct < 3; ++ct) {
                float wvv = wvrow[256 + ct];
                a0 += wvv * w_lds[(0 * NHEAD + h) * CP + 256 + ct];
                a1 += wvv * w_lds[(1 * NHEAD + h) * CP + 256 + ct];
                a2 += wvv * w_lds[(2 * NHEAD + h) * CP + 256 + ct];
                a3 += wvv * w_lds[(3 * NHEAD + h) * CP + 256 + ct];
            }
        }
        #pragma unroll
        for (int off = 1; off <= 4; off <<= 1) {
            a0 += __shfl_xor(a0, off, 64);
            a1 += __shfl_xor(a1, off, 64);
            a2 += __shfl_xor(a2, off, 64);
            a3 += __shfl_xor(a3, off, 64);
        }
        float val = (cs == 0) ? a0 : (cs == 1) ? a1 : (cs == 2) ? a2 : a3;
        if (cs < 4) uni[cs * 256 + row] = val;  // out slot (att dead)
    }
    __syncthreads();

    // ---- P5: final[nb][row] = sum_dd Wo[row][dd] * out[nb][dd]  (coalesced split-K)
    #pragma unroll
    for (int p = 0; p < 8; ++p) {
        const int row = p * 32 + wv * 8 + dr;
        const float* worow = Wo + (size_t)row * H;
        float a0 = 0.f, a1 = 0.f, a2 = 0.f, a3 = 0.f;
        #pragma unroll
        for (int m = 0; m < 8; ++m) {
            float4 wo = *(const float4*)&worow[cs * 4 + 32 * m];
            a0 += dot4(wo, *(const float4*)&uni[0 * 256 + cs * 4 + 32 * m]);
            a1 += dot4(wo, *(const float4*)&uni[1 * 256 + cs * 4 + 32 * m]);
            a2 += dot4(wo, *(const float4*)&uni[2 * 256 + cs * 4 + 32 * m]);
            a3 += dot4(wo, *(const float4*)&uni[3 * 256 + cs * 4 + 32 * m]);
        }
        #pragma unroll
        for (int off = 1; off <= 4; off <<= 1) {
            a0 += __shfl_xor(a0, off, 64);
            a1 += __shfl_xor(a1, off, 64);
            a2 += __shfl_xor(a2, off, 64);
            a3 += __shfl_xor(a3, off, 64);
        }
        float val = (cs == 0) ? a0 : (cs == 1) ? a1 : (cs == 2) ? a2 : a3;
        if (cs < 4 && (n0 + cs) < n) outp[(size_t)(n0 + cs) * H + row] = val;
    }
}

} // anonymous namespace

extern "C" void kernel_launch(void* const* d_in, const int* in_sizes, int n_in,
                              void* d_out, int out_size, void* d_ws, size_t ws_size,
                              hipStream_t stream) {
    const float* q  = (const float*)d_in[0];
    const float* k  = (const float*)d_in[1];
    const float* v  = (const float*)d_in[2];
    const float* Wq = (const float*)d_in[3];
    const float* Wk = (const float*)d_in[4];
    const float* Wv = (const float*)d_in[5];
    const float* Wo = (const float*)d_in[6];
    float* out = (float*)d_out;

    const int n = in_sizes[0] / H;            // 10000 nodes
    const int blocks = (n + NB - 1) / NB;     // 2500

    mha_neigh_kernel<<<dim3(blocks), dim3(256), 0, stream>>>(
        q, k, v, Wq, Wk, Wv, Wo, out, n);
}